// Round 3
// baseline (286.577 us; speedup 1.0000x reference)
//
#include <hip/hip_runtime.h>
#include <cstdint>
#include <cstddef>

#define BATCH 64
#define NIN   1024
#define CIN   256
#define NC    32
#define NJC   16     // j-chunks per batch
#define JCH   64     // NIN/NJC
#define SUBJ  16     // j per LDS stage
#define NSUB  4      // JCH/SUBJ
#define WTPH  260    // padded wts row in bf16 shorts (520B: 2-way-conflict = free)
#define T_EPS 1e-7f

__device__ __forceinline__ unsigned short bf16rne(float f) {
  unsigned int u = __float_as_uint(f);
  u += 0x7FFFu + ((u >> 16) & 1u);
  return (unsigned short)(u >> 16);
}
__device__ __forceinline__ float bf2f(unsigned short h) {
  return __uint_as_float(((unsigned int)h) << 16);
}

// ---------- K1: partial column sums of x over j (iter-0 uniform routing) ----
__global__ __launch_bounds__(256) void k_colsum(const float* __restrict__ x,
                                                float* __restrict__ y0p) {
  const int b = blockIdx.y, jc = blockIdx.x, t = threadIdx.x;
  const float* xp = x + ((size_t)(b * NIN + jc * JCH)) * CIN + t;
  float a0 = 0.f, a1 = 0.f, a2 = 0.f, a3 = 0.f;
  for (int j = 0; j < JCH; j += 4) {
    a0 += xp[(size_t)(j + 0) * CIN];
    a1 += xp[(size_t)(j + 1) * CIN];
    a2 += xp[(size_t)(j + 2) * CIN];
    a3 += xp[(size_t)(j + 3) * CIN];
  }
  y0p[(b * NJC + jc) * CIN + t] = (a0 + a1) + (a2 + a3);
}

// ---------- K2: fused y-reduce -> s = y@W_i -> squash -> wt(bf16) or out ----
// grid (i=NC, b=BATCH); block 256. MODE 0: yin=y0p fp32 (i-independent).
// MODE 1: yin=ypart bf16 (q/sl/i layout), write wt. MODE 2: same yin, write out.
template <int MODE>
__global__ __launch_bounds__(256) void k_post(const void* __restrict__ yin,
                                              const float* __restrict__ W,
                                              unsigned short* __restrict__ wtout,
                                              float* __restrict__ outg) {
  const int i = blockIdx.x, b = blockIdx.y, t = threadIdx.x;
  __shared__ float Wl[CIN][36];   // W[c, i*32+k]; stride 36 -> 16B-aligned rows
  __shared__ float ys[CIN];
  __shared__ float sred[8][32];
  __shared__ float os[NC];
  // stage W block for capsule i (each 8-lane group reads 128B contiguous)
  const float4* W4 = (const float4*)W;
  #pragma unroll
  for (int q = 0; q < 8; ++q) {
    int f = q * 256 + t;            // 0..2047
    int c = f >> 3, k4 = f & 7;
    float4 v = W4[c * (NC * 8) + i * 8 + k4];
    *(float4*)&Wl[c][k4 * 4] = v;
  }
  // reduce partial y for this (b, i); lane t <-> c
  float a = 0.f;
  if (MODE == 0) {
    const float* y0p = (const float*)yin;
    #pragma unroll
    for (int p = 0; p < NJC; ++p) a += y0p[(b * NJC + p) * CIN + t];
    a *= (1.f / 32.f);
  } else {
    const unsigned short* yp = (const unsigned short*)yin;
    const int q = (t >> 2) & 7, sl = t >> 5, k = t & 3;
    #pragma unroll
    for (int p = 0; p < NJC; ++p)
      a += bf2f(yp[(((((size_t)(b * NJC + p)) * 8 + q) * 8 + sl) * 32 + i) * 4 + k]);
  }
  ys[t] = a;
  __syncthreads();
  // s[k] = sum_c ys[c] * Wl[c][k]; 8 c-groups of 32, k = t&31
  {
    const int k = t & 31, g = t >> 5;
    float ps = 0.f;
    #pragma unroll
    for (int cc = 0; cc < 32; ++cc) {
      int c = g * 32 + cc;
      ps += ys[c] * Wl[c][k];     // banks (4c+k)%32: conflict-free
    }
    sred[g][k] = ps;
  }
  __syncthreads();
  const int k = t & 31;
  float s = 0.f;
  #pragma unroll
  for (int g = 0; g < 8; ++g) s += sred[g][k];
  float s2 = s * s;
  #pragma unroll
  for (int m = 1; m < 32; m <<= 1) s2 += __shfl_xor(s2, m);
  float o = s * rsqrtf(s2 + T_EPS);
  if (MODE == 2) {
    if (t < 32) outg[((size_t)b * NC + i) * 32 + t] = o;
  } else {
    if (t < 32) os[t] = o;
    __syncthreads();
    // wt[b,i,c] = sum_k W[c,ik] * o[k];  c = t; rotate k-start to kill
    // the 8-way conflict from row-stride 36 (bank stride 4)
    const int rot = ((t >> 3) & 7) * 4;
    float acc = 0.f;
    #pragma unroll
    for (int kkk = 0; kkk < 32; ++kkk) {
      int kk = (kkk + rot) & 31;
      acc += Wl[t][kk] * os[kk];
    }
    wtout[((size_t)b * NC + i) * CIN + t] = bf16rne(acc);
  }
}

// ---------- K3: fused  b = x@wt^T -> softmax(i) -> ypart = c^T@x ----------
// ypart layout: [b][jc][q:8][sl:8][i:32] of ushort4 (bf16 x4) -> 512B/wave-instr
__global__ __launch_bounds__(256, 4) void k_fused(const float* __restrict__ x,
                                                  const unsigned short* __restrict__ wt,
                                                  ushort4* __restrict__ ypart) {
  const int b = blockIdx.y, jc = blockIdx.x, t = threadIdx.x;
  __shared__ unsigned short wts[NC][WTPH];  // bf16, 16.6 KB
  __shared__ float xs[SUBJ][CIN];           // 16 KB
  __shared__ float cs[SUBJ][33];            // 2.1 KB   total 34.8 KB -> 4 blk/CU
  const int i  = t & 31;   // capsule (phase A logits & phase B row)
  const int sl = t >> 5;   // j-slot (phase A) / c-block (phase B)

  // register prefetch of x sub-chunk 0 (issue before wt staging)
  const float4* xg0 = (const float4*)(x + ((size_t)(b * NIN + jc * JCH)) * CIN);
  float4 xp[4];
  #pragma unroll
  for (int q = 0; q < 4; ++q) xp[q] = xg0[q * 256 + t];

  {  // stage wt (already bf16 in global)
    const ushort4* wtg = (const ushort4*)(wt + (size_t)b * NC * CIN);
    #pragma unroll
    for (int q = 0; q < 8; ++q) {
      int f = q * 256 + t;                  // 0..2047 ushort4s
      *(ushort4*)&wts[f >> 6][(f & 63) * 4] = wtg[f];
    }
  }
  float4 accB[8];
  #pragma unroll
  for (int q = 0; q < 8; ++q) accB[q] = make_float4(0.f, 0.f, 0.f, 0.f);

  for (int sub = 0; sub < NSUB; ++sub) {
    __syncthreads();  // xs/cs free (prev phase B done)
    #pragma unroll
    for (int q = 0; q < 4; ++q) {
      int f = q * 256 + t;                  // 0..1023 float4s
      *(float4*)&xs[f >> 6][(f & 63) * 4] = xp[q];
    }
    if (sub + 1 < NSUB) {                   // prefetch next chunk
      const float4* xg = xg0 + (size_t)(sub + 1) * (SUBJ * CIN / 4);
      #pragma unroll
      for (int q = 0; q < 4; ++q) xp[q] = xg[q * 256 + t];
    }
    __syncthreads();
    // phase A: logits for j = sl and j = 8+sl (xs reads are 2-addr broadcasts)
    float b1 = 0.f, b2 = 0.f;
    #pragma unroll 8
    for (int c4 = 0; c4 < 64; ++c4) {
      uint2 wp = *(const uint2*)&wts[i][c4 * 4];
      float4 xa = *(const float4*)&xs[sl][c4 * 4];
      float4 xb = *(const float4*)&xs[8 + sl][c4 * 4];
      float w0 = __uint_as_float(wp.x << 16);
      float w1 = __uint_as_float(wp.x & 0xFFFF0000u);
      float w2 = __uint_as_float(wp.y << 16);
      float w3 = __uint_as_float(wp.y & 0xFFFF0000u);
      b1 += w0 * xa.x + w1 * xa.y + w2 * xa.z + w3 * xa.w;
      b2 += w0 * xb.x + w1 * xb.y + w2 * xb.z + w3 * xb.w;
    }
    // softmax over 32 capsules within each 32-lane half-wave
    float m1 = b1, m2 = b2;
    #pragma unroll
    for (int m = 1; m < 32; m <<= 1) {
      m1 = fmaxf(m1, __shfl_xor(m1, m));
      m2 = fmaxf(m2, __shfl_xor(m2, m));
    }
    float e1 = __expf(b1 - m1), e2 = __expf(b2 - m2);
    float s1 = e1, s2 = e2;
    #pragma unroll
    for (int m = 1; m < 32; m <<= 1) {
      s1 += __shfl_xor(s1, m);
      s2 += __shfl_xor(s2, m);
    }
    cs[sl][i]     = e1 / s1;
    cs[8 + sl][i] = e2 / s2;
    __syncthreads();
    // phase B: y[i, sl*32..+31] += sum_j c[j,i] * x[j,:]
    #pragma unroll
    for (int j = 0; j < SUBJ; ++j) {
      float cv = cs[j][i];
      #pragma unroll
      for (int q = 0; q < 8; ++q) {
        float4 xv = *(const float4*)&xs[j][sl * 32 + q * 4];
        accB[q].x += cv * xv.x; accB[q].y += cv * xv.y;
        accB[q].z += cv * xv.z; accB[q].w += cv * xv.w;
      }
    }
  }
  // epilogue: bf16 partials, coalesced (per q: wave covers 512B contiguous)
  ushort4* yp = ypart + ((size_t)(b * NJC + jc)) * (8 * 8 * 32);
  #pragma unroll
  for (int q = 0; q < 8; ++q) {
    ushort4 h;
    h.x = bf16rne(accB[q].x); h.y = bf16rne(accB[q].y);
    h.z = bf16rne(accB[q].z); h.w = bf16rne(accB[q].w);
    yp[(q * 8 + sl) * 32 + i] = h;
  }
}

extern "C" void kernel_launch(void* const* d_in, const int* in_sizes, int n_in,
                              void* d_out, int out_size, void* d_ws, size_t ws_size,
                              hipStream_t stream) {
  (void)in_sizes; (void)n_in; (void)out_size; (void)ws_size;
  const float* x = (const float*)d_in[0];
  const float* W = (const float*)d_in[1];
  float* out = (float*)d_out;
  char* ws = (char*)d_ws;
  // ws layout: wt (bf16, 1MB) | ypart (bf16 q/sl/i layout, 16.8MB); y0p aliases ypart
  unsigned short* wt = (unsigned short*)ws;
  ushort4* ypart = (ushort4*)(ws + (1u << 20));
  float* y0p = (float*)(ws + (1u << 20));   // dead before first k_fused write

  dim3 gchunks(NJC, BATCH);   // (16, 64)
  dim3 gpost(NC, BATCH);      // (32, 64)
  k_colsum<<<gchunks, 256, 0, stream>>>(x, y0p);
  k_post<0><<<gpost, 256, 0, stream>>>(y0p, W, wt, nullptr);     // iter 0
  k_fused<<<gchunks, 256, 0, stream>>>(x, wt, ypart);            // iter 1 routing
  k_post<1><<<gpost, 256, 0, stream>>>(ypart, W, wt, nullptr);
  k_fused<<<gchunks, 256, 0, stream>>>(x, wt, ypart);            // iter 2 routing
  k_post<2><<<gpost, 256, 0, stream>>>(ypart, W, nullptr, out);
}

// Round 4
// 156.364 us; speedup vs baseline: 1.8328x; 1.8328x over previous
//
#include <hip/hip_runtime.h>
#include <cstdint>
#include <cstddef>

#define BATCH 64
#define NIN   1024
#define CIN   256
#define NC    32
#define NJC   16     // j-blocks per batch for k_fused (64 j each)
#define JCH   64
#define NP0   8      // colsum partial count
#define T_EPS 1e-7f

// LDS row strides in u16 units (rows must be 16B-aligned for b128 reads)
#define WTS_S 264    // 528 B
#define XT_S  72     // 144 B
#define CT_S  72     // 144 B

typedef __attribute__((ext_vector_type(8))) short short8;   // 8 bf16 = 4 VGPR
typedef __attribute__((ext_vector_type(4))) float floatx4;  // MFMA 16x16 acc

__device__ __forceinline__ unsigned short bf16rne(float f) {
  unsigned int u = __float_as_uint(f);
  u += 0x7FFFu + ((u >> 16) & 1u);
  return (unsigned short)(u >> 16);
}
__device__ __forceinline__ float bf2f(unsigned short h) {
  return __uint_as_float(((unsigned int)h) << 16);
}

// ---- K1: x fp32 -> bf16 copy + partial column sums (iter-0 uniform c) ----
__global__ __launch_bounds__(256) void k_convert(const float* __restrict__ x,
                                                 unsigned short* __restrict__ xb,
                                                 float* __restrict__ y0p) {
  const int b = blockIdx.y, g = blockIdx.x, t = threadIdx.x;
  const size_t base = ((size_t)(b * NIN + g * 128)) * CIN + t;
  const float* xp = x + base;
  unsigned short* xo = xb + base;
  float acc = 0.f;
  #pragma unroll 8
  for (int j = 0; j < 128; ++j) {
    float v = xp[(size_t)j * CIN];
    acc += v;
    xo[(size_t)j * CIN] = bf16rne(v);
  }
  y0p[(b * NP0 + g) * CIN + t] = acc;
}

// ---- K2: y-reduce -> s = y@W_i -> squash -> wt(bf16) or out --------------
// grid (i=NC, b=BATCH). MODE 0: yin = y0p fp32 (NP0 partials, scale 1/32).
// MODE 1: yin = ypart bf16 [b][jc][i][c], write wt. MODE 2: write out.
template <int MODE>
__global__ __launch_bounds__(256) void k_post(const void* __restrict__ yin,
                                              const float* __restrict__ W,
                                              unsigned short* __restrict__ wtout,
                                              float* __restrict__ outg) {
  const int i = blockIdx.x, b = blockIdx.y, t = threadIdx.x;
  __shared__ float Wl[CIN][36];
  __shared__ float ys[CIN];
  __shared__ float sred[8][32];
  __shared__ float os[NC];
  const float4* W4 = (const float4*)W;
  #pragma unroll
  for (int q = 0; q < 8; ++q) {
    int f = q * 256 + t;            // 0..2047
    int c = f >> 3, k4 = f & 7;
    float4 v = W4[c * (NC * 8) + i * 8 + k4];
    *(float4*)&Wl[c][k4 * 4] = v;
  }
  float a = 0.f;
  if (MODE == 0) {
    const float* y0p = (const float*)yin;
    #pragma unroll
    for (int p = 0; p < NP0; ++p) a += y0p[(b * NP0 + p) * CIN + t];
    a *= (1.f / 32.f);
  } else {
    const unsigned short* yp = (const unsigned short*)yin;
    #pragma unroll
    for (int p = 0; p < NJC; ++p)
      a += bf2f(yp[(((size_t)(b * NJC + p)) * NC + i) * CIN + t]);
  }
  ys[t] = a;
  __syncthreads();
  {
    const int k = t & 31, g = t >> 5;
    float ps = 0.f;
    #pragma unroll
    for (int cc = 0; cc < 32; ++cc) {
      int c = g * 32 + cc;
      ps += ys[c] * Wl[c][k];
    }
    sred[g][k] = ps;
  }
  __syncthreads();
  const int k = t & 31;
  float s = 0.f;
  #pragma unroll
  for (int g = 0; g < 8; ++g) s += sred[g][k];
  float s2 = s * s;
  #pragma unroll
  for (int m = 1; m < 32; m <<= 1) s2 += __shfl_xor(s2, m);
  float o = s * rsqrtf(s2 + T_EPS);
  if (MODE == 2) {
    if (t < 32) outg[((size_t)b * NC + i) * 32 + t] = o;
  } else {
    if (t < 32) os[t] = o;
    __syncthreads();
    const int rot = ((t >> 3) & 7) * 4;
    float acc = 0.f;
    #pragma unroll
    for (int kkk = 0; kkk < 32; ++kkk) {
      int kk = (kkk + rot) & 31;
      acc += Wl[t][kk] * os[kk];
    }
    wtout[((size_t)b * NC + i) * CIN + t] = bf16rne(acc);
  }
}

// ---- K3: MFMA-fused  L = wt@x^T -> softmax(i) -> y = c@x -----------------
// block = (jc, b): 64 j's, 4 waves (wave w: j-tile w*16..+15; phase-B c-range
// w*64..+63). mfma_f32_16x16x32_bf16 layouts:
//   A: lane L -> row m=L&15, k=(L>>4)*8+e ; B: col n=L&15, k=(L>>4)*8+e
//   C/D: col n=L&15, row m=(L>>4)*4+reg   (m89/m91-verified)
__global__ __launch_bounds__(256) void k_fused(const unsigned short* __restrict__ xb,
                                               const unsigned short* __restrict__ wt,
                                               unsigned short* __restrict__ ypart) {
  const int jc = blockIdx.x, b = blockIdx.y, t = threadIdx.x;
  const int w = t >> 6, lane = t & 63;
  const int l16 = lane & 15, q = lane >> 4;   // quad 0..3
  __shared__ unsigned short wts[NC * WTS_S];  // 16.9 KB
  __shared__ unsigned short xT[CIN * XT_S];   // 36.9 KB  x^T[c][j] bf16
  __shared__ unsigned short cT[NC * CT_S];    // 4.6 KB   c[i][j]  bf16
  // stage wt[b] (32 x 256 bf16)
  {
    const ushort4* wg = (const ushort4*)(wt + (size_t)b * NC * CIN);
    #pragma unroll
    for (int it = 0; it < 8; ++it) {
      int f = it * 256 + t;         // 0..2047 ushort4 units; row = 64 of them
      int i = f >> 6, o4 = f & 63;
      *(ushort4*)&wts[i * WTS_S + o4 * 4] = wg[f];
    }
  }
  const int jloc = w * 16 + l16;    // block-local j for this lane's B column
  const unsigned short* xrow =
      xb + ((size_t)(b * NIN) + (size_t)jc * JCH + jloc) * CIN;
  // prefetch first two B-frags (independent of LDS staging)
  short8 bfr[2];
  bfr[0] = *(const short8*)(xrow + 0 * 32 + q * 8);
  bfr[1] = *(const short8*)(xrow + 1 * 32 + q * 8);
  floatx4 accA0 = {0.f, 0.f, 0.f, 0.f}, accA1 = {0.f, 0.f, 0.f, 0.f};
  __syncthreads();
  // phase A: logits over c=256 (8 K-steps of 32)
  #pragma unroll
  for (int ks = 0; ks < 8; ++ks) {
    short8 bcur = bfr[ks & 1];
    if (ks < 6) bfr[ks & 1] = *(const short8*)(xrow + (ks + 2) * 32 + q * 8);
    short8 a0 = *(const short8*)&wts[l16 * WTS_S + ks * 32 + q * 8];
    short8 a1 = *(const short8*)&wts[(16 + l16) * WTS_S + ks * 32 + q * 8];
    accA0 = __builtin_amdgcn_mfma_f32_16x16x32_bf16(a0, bcur, accA0, 0, 0, 0);
    accA1 = __builtin_amdgcn_mfma_f32_16x16x32_bf16(a1, bcur, accA1, 0, 0, 0);
    // build x^T from the B-frag we just consumed
    #pragma unroll
    for (int e = 0; e < 8; ++e) {
      int c = ks * 32 + q * 8 + e;
      xT[c * XT_S + jloc] = (unsigned short)bcur[e];
    }
  }
  // softmax over i (32 capsules) for column j=jloc:
  // lane holds rows {q*4+r} (accA0) and {16+q*4+r} (accA1); quads via shfl.
  {
    float m = accA0[0];
    #pragma unroll
    for (int r = 1; r < 4; ++r) m = fmaxf(m, accA0[r]);
    #pragma unroll
    for (int r = 0; r < 4; ++r) m = fmaxf(m, accA1[r]);
    m = fmaxf(m, __shfl_xor(m, 16));
    m = fmaxf(m, __shfl_xor(m, 32));
    float e0[4], e1[4], s = 0.f;
    #pragma unroll
    for (int r = 0; r < 4; ++r) {
      e0[r] = __expf(accA0[r] - m);
      e1[r] = __expf(accA1[r] - m);
      s += e0[r] + e1[r];
    }
    s += __shfl_xor(s, 16);
    s += __shfl_xor(s, 32);
    float rs = 1.f / s;
    #pragma unroll
    for (int r = 0; r < 4; ++r) {
      cT[(q * 4 + r) * CT_S + jloc]        = bf16rne(e0[r] * rs);
      cT[(16 + q * 4 + r) * CT_S + jloc]   = bf16rne(e1[r] * rs);
    }
  }
  __syncthreads();   // xT + cT complete, visible to all waves
  // phase B: y[i, cw..cw+63] = sum_j c[i,j] x[j,c]  (K=64 j's, 2 K-steps)
  const int cw = w * 64;
  floatx4 accB[2][4];
  #pragma unroll
  for (int it = 0; it < 2; ++it)
    #pragma unroll
    for (int ct = 0; ct < 4; ++ct) accB[it][ct] = (floatx4){0.f, 0.f, 0.f, 0.f};
  #pragma unroll
  for (int ks = 0; ks < 2; ++ks) {
    short8 ca0 = *(const short8*)&cT[l16 * CT_S + ks * 32 + q * 8];
    short8 ca1 = *(const short8*)&cT[(16 + l16) * CT_S + ks * 32 + q * 8];
    #pragma unroll
    for (int ct = 0; ct < 4; ++ct) {
      short8 xf = *(const short8*)&xT[(cw + ct * 16 + l16) * XT_S + ks * 32 + q * 8];
      accB[0][ct] = __builtin_amdgcn_mfma_f32_16x16x32_bf16(ca0, xf, accB[0][ct], 0, 0, 0);
      accB[1][ct] = __builtin_amdgcn_mfma_f32_16x16x32_bf16(ca1, xf, accB[1][ct], 0, 0, 0);
    }
  }
  // epilogue: bf16 partial y for this block
  unsigned short* yo = ypart + ((size_t)(b * NJC + jc)) * NC * CIN;
  #pragma unroll
  for (int it = 0; it < 2; ++it)
    #pragma unroll
    for (int ct = 0; ct < 4; ++ct)
      #pragma unroll
      for (int r = 0; r < 4; ++r) {
        int i = it * 16 + q * 4 + r;
        int c = cw + ct * 16 + l16;
        yo[i * CIN + c] = bf16rne(accB[it][ct][r]);
      }
}

extern "C" void kernel_launch(void* const* d_in, const int* in_sizes, int n_in,
                              void* d_out, int out_size, void* d_ws, size_t ws_size,
                              hipStream_t stream) {
  (void)in_sizes; (void)n_in; (void)out_size; (void)ws_size;
  const float* x = (const float*)d_in[0];
  const float* W = (const float*)d_in[1];
  float* out = (float*)d_out;
  char* ws = (char*)d_ws;
  // ws: xb bf16 33.6MB | wt bf16 1MB | ypart bf16 16.8MB | y0p fp32 0.5MB
  unsigned short* xbuf  = (unsigned short*)ws;
  unsigned short* wtb   = (unsigned short*)(ws + (34ull << 20));
  unsigned short* ypart = (unsigned short*)(ws + (35ull << 20));
  float*          y0p   = (float*)(ws + (52ull << 20));

  dim3 gconv(NP0, BATCH);     // (8, 64)
  dim3 gfuse(NJC, BATCH);     // (16, 64)
  dim3 gpost(NC, BATCH);      // (32, 64)
  k_convert<<<gconv, 256, 0, stream>>>(x, xbuf, y0p);
  k_post<0><<<gpost, 256, 0, stream>>>(y0p, W, wtb, nullptr);     // iter 0
  k_fused<<<gfuse, 256, 0, stream>>>(xbuf, wtb, ypart);           // iter 1
  k_post<1><<<gpost, 256, 0, stream>>>(ypart, W, wtb, nullptr);
  k_fused<<<gfuse, 256, 0, stream>>>(xbuf, wtb, ypart);           // iter 2
  k_post<2><<<gpost, 256, 0, stream>>>(ypart, W, nullptr, out);
}